// Round 9
// baseline (86.825 us; speedup 1.0000x reference)
//
#include <hip/hip_runtime.h>
#include <math.h>

#define HI 240
#define WI 135
#define NPIX (HI * WI)          // 32400
#define NF 1000
#define BLK 256
#define TW 8                    // tile width (px)
#define TH 8                    // tile height (px)
#define TX_N 17                 // ceil(135/8)
#define TY_N 30                 // 240/8
#define NTILE (TX_N * TY_N)     // 510
#define TPB 4                   // tiles (waves) per block
#define NBX ((NTILE + TPB - 1) / TPB)   // 128 blocks, 1 per CU max

// LDS face table: 14 SoA arrays of NF floats (56 KB). SoA -> stride-1 lane
// gather in the scan (conflict-free); wave-uniform broadcast in eval.
//   0 bx0, 1 by0, 2 bx1, 3 by1, 4 flag(0=dead, +-1=orientation, 2=patho),
//   5 p0x, 6 p0y, 7 p1x, 8 p1y, 9 p2x, 10 p2y, 11 rd0, 12 rd1, 13 rd2
// Edges are recomputed from p's by exact float subtraction, so the
// sign-test crosses remain bitwise-identical to the reference.

__device__ __forceinline__ void project(float x, float y, float z,
                                        float& px, float& py) {
#pragma clang fp contract(off)
    // Bitwise-mirrors ref: z=max(v_z,1e-6); px=(1000*(-x)/z + 512)/1024*W; etc.
    float zc = fmaxf(z, 1e-6f);
    px = ((1000.0f * (-x)) / zc + 512.0f) / 1024.0f * (float)WI;
    py = ((1000.0f * (-y)) / zc + 512.0f) / 1024.0f * (float)HI;
}

// One face evaluation; bitwise-matches the reference on the sign-test cliff
// (crosses), fast-math on the smooth parts (2e-2 slack). tz-invalid faces
// never reach here (empty bbox), so 'valid' needs no tz term.
__device__ __forceinline__ float eval_face(const float S[14][NF], int f,
                                           float px, float py)
{
    float p0x = S[5][f], p0y = S[6][f];
    float p1x = S[7][f], p1y = S[8][f];
    float p2x = S[9][f], p2y = S[10][f];
    float rd0 = S[11][f], rd1 = S[12][f], rd2 = S[13][f];

    float e0x = p1x - p0x, e0y = p1y - p0y;   // exact subs = prep's values
    float e1x = p2x - p1x, e1y = p2y - p1y;
    float e2x = p0x - p2x, e2y = p0y - p2y;

    float a0x = px - p0x, a0y = py - p0y;
    float a1x = px - p1x, a1y = py - p1y;
    float a2x = px - p2x, a2y = py - p2y;

    float c0, c1, c2;
    {
#pragma clang fp contract(off)
        c0 = e0x * a0y - e0y * a0x;
        c1 = e1x * a1y - e1y * a1x;
        c2 = e2x * a2y - e2y * a2x;
    }
    bool pos = (c0 >= 0.0f) & (c1 >= 0.0f) & (c2 >= 0.0f);
    bool neg = (c0 <= 0.0f) & (c1 <= 0.0f) & (c2 <= 0.0f);

    float t0 = fminf(fmaxf((a0x * e0x + a0y * e0y) * rd0, 0.0f), 1.0f);
    float t1 = fminf(fmaxf((a1x * e1x + a1y * e1y) * rd1, 0.0f), 1.0f);
    float t2 = fminf(fmaxf((a2x * e2x + a2y * e2y) * rd2, 0.0f), 1.0f);
    float u0x = a0x - t0 * e0x, u0y = a0y - t0 * e0y;
    float u1x = a1x - t1 * e1x, u1y = a1y - t1 * e1y;
    float u2x = a2x - t2 * e2x, u2y = a2y - t2 * e2y;
    float d20 = u0x * u0x + u0y * u0y;
    float d21 = u1x * u1x + u1y * u1y;
    float d22 = u2x * u2x + u2y * u2y;
    float d2m = fminf(d20, fminf(d21, d22));

    bool inside = pos | neg;
    float uu = (inside ? d2m : -d2m) * 1.0e4f;
    bool valid = inside | (d2m <= 9.2102404e-4f);
    float sp;
    if (uu > 16.0f) sp = uu;     // softplus(uu)=uu to <1.2e-7
    else sp = fmaxf(uu, 0.0f) + __logf(1.0f + __expf(-fabsf(uu)));
    return valid ? sp : 0.0f;
}

// Structure notes (R2/R4/R5/R6/R7/R8 post-mortems):
//  - NO device-scope fences / global atomics in the hot path (R2 fence storm).
//  - Fused staging (R8: separate prep kernel + global round-trip was -5.5us
//    WORSE — recompute in-block is cheaper than cross-XCD L3 reads).
//  - R9: one wave owns its 8x8 tile COMPLETELY (NCHUNK=1). Alpha computed
//    in-register; out[1+q] plain store; one loss partial per block. Kills
//    the ws partial round-trip, a dispatch, and 10/11ths of the blocks.
//  - Alpha-saturation early exit (all lanes <= -30 -> alpha bitwise 1.0f for
//    both ref and kernel) now skips remaining SCAN rounds too.
//  - SAT tile/triangle cull + 2-wide ILP eval (R7).
__global__ __launch_bounds__(BLK) void sil_kernel(
    const float* __restrict__ verts, const int* __restrict__ faces,
    const float* __restrict__ gt, float* __restrict__ out,
    float* __restrict__ ws)
{
    __shared__ float S[14][NF];     // 56 KB
    __shared__ float wsum[TPB];

    // ---- staging: 4 faces per thread, recomputed in-block ----
    for (int f = threadIdx.x; f < NF; f += BLK) {
#pragma clang fp contract(off)
        int i0 = faces[3 * f + 0], i1 = faces[3 * f + 1], i2 = faces[3 * f + 2];
        float x0 = verts[3 * i0 + 0], y0 = verts[3 * i0 + 1], z0 = verts[3 * i0 + 2];
        float x1 = verts[3 * i1 + 0], y1 = verts[3 * i1 + 1], z1 = verts[3 * i1 + 2];
        float x2 = verts[3 * i2 + 0], y2 = verts[3 * i2 + 1], z2 = verts[3 * i2 + 2];

        float p0x, p0y, p1x, p1y, p2x, p2y;
        project(x0, y0, z0, p0x, p0y);
        project(x1, y1, z1, p1x, p1y);
        project(x2, y2, z2, p2x, p2y);

        float e0x = p1x - p0x, e0y = p1y - p0y;
        float e1x = p2x - p1x, e1y = p2y - p1y;
        float e2x = p0x - p2x, e2y = p0y - p2y;
        float den0 = (e0x * e0x + e0y * e0y) + 1e-12f;
        float den1 = (e1x * e1x + e1y * e1y) + 1e-12f;
        float den2 = (e2x * e2x + e2y * e2y) + 1e-12f;

        float tz = ((z0 + z1) + z2) / 3.0f;
        bool tzok = tz > 1e-6f;

        // Pathology rule (provable): fp cross sign flip outside bbox+0.3px
        // needs two simultaneously-ambiguous crosses; safe iff
        // area2 >= 4e-3*lmax^2 and lmax <= 2000px. Unsafe: infinite bbox,
        // no SAT cull, evaluated everywhere (bitwise-matching arithmetic).
        float orient = e0x * e1y - e0y * e1x;   // 2*signed area
        float area2 = fabsf(orient);
        float l2max = fmaxf(den0, fmaxf(den1, den2));
        bool dup = (i0 == i1) || (i1 == i2) || (i2 == i0);
        bool patho = dup || (area2 < 4.0e-3f * l2max) || (l2max > 4.0e6f);

        float bx0, by0, bx1, by1, flag;
        if (!tzok) {               // contribution exactly zero everywhere
            bx0 = 1e30f; by0 = 1e30f; bx1 = -1e30f; by1 = -1e30f; flag = 0.0f;
        } else if (patho) {        // always evaluate
            bx0 = -1e30f; by0 = -1e30f; bx1 = 1e30f; by1 = 1e30f; flag = 2.0f;
        } else {
            // 0.3 px margin >= sqrt(BLUR)=0.0304 blur band + fp band
            bx0 = fminf(p0x, fminf(p1x, p2x)) - 0.3f;
            by0 = fminf(p0y, fminf(p1y, p2y)) - 0.3f;
            bx1 = fmaxf(p0x, fmaxf(p1x, p2x)) + 0.3f;
            by1 = fmaxf(p0y, fmaxf(p1y, p2y)) + 0.3f;
            flag = (orient >= 0.0f) ? 1.0f : -1.0f;   // orientation sign
        }

        S[0][f] = bx0;  S[1][f] = by0;  S[2][f] = bx1;  S[3][f] = by1;
        S[4][f] = flag;
        S[5][f] = p0x;  S[6][f] = p0y;
        S[7][f] = p1x;  S[8][f] = p1y;
        S[9][f] = p2x;  S[10][f] = p2y;
        S[11][f] = 1.0f / den0;  S[12][f] = 1.0f / den1;  S[13][f] = 1.0f / den2;
    }
    __syncthreads();

    int wave = threadIdx.x >> 6, lane = threadIdx.x & 63;
    int tile = blockIdx.x * TPB + wave;
    bool wave_active = tile < NTILE;     // 2 dead waves in the last block

    float c = 0.0f;                      // per-lane |alpha - gt|
    if (wave_active) {
        int ty = tile / TX_N, tx = tile - ty * TX_N;
        int col = tx * TW + (lane & 7);
        int row = ty * TH + (lane >> 3);
        bool live = col < WI;            // x-tail tiles partially valid
        int q = row * WI + col;
        float px = (float)col + 0.5f;
        float py = (float)row + 0.5f;
        // wave-uniform 8x8 tile rect (pixel centers)
        float wx0 = (float)(tx * TW) + 0.5f, wx1 = (float)(tx * TW + TW - 1) + 0.5f;
        float wy0 = (float)(ty * TH) + 0.5f, wy1 = (float)(ty * TH + TH - 1) + 0.5f;

        // dead lanes start saturated so they never block the early-exit ballot
        float sum = live ? 0.0f : -1e30f;
        bool done = false;

        for (int r = 0; r < (NF + 63) / 64 && !done; ++r) {
            int fl = r * 64 + lane;
            bool ov = false;
            if (fl < NF) {
                ov = !(S[0][fl] > wx1 || S[2][fl] < wx0 ||
                       S[1][fl] > wy1 || S[3][fl] < wy0);
                float flg = S[4][fl];
                if (ov && flg != 2.0f) {
                    // SAT: rect separated from triangle by edge k's line with
                    // >0.3px margin -> exactly zero contribution for the
                    // whole tile. Cross affine in p: max over rect corners =
                    // base + max(0,-7*sEy) + max(0,7*sEx).
                    float sgn = flg;     // +-1
                    bool cull = false;
#pragma unroll
                    for (int k = 0; k < 3; ++k) {
                        int kn = (k == 2) ? 0 : (k + 1);
                        float Px = S[5 + 2 * k][fl], Py = S[6 + 2 * k][fl];
                        float Ex = S[5 + 2 * kn][fl] - Px;
                        float Ey = S[6 + 2 * kn][fl] - Py;
                        float sEx = sgn * Ex, sEy = sgn * Ey;
                        float base = sEx * (wy0 - Py) - sEy * (wx0 - Px);
                        float mx = base + fmaxf(0.0f, -7.0f * sEy)
                                        + fmaxf(0.0f,  7.0f * sEx);
                        cull |= (mx < 0.0f) & (mx * mx * S[11 + k][fl] > 0.09f);
                    }
                    ov = !cull;
                }
            }
            unsigned long long m = __ballot(ov);

            while (m) {
                // pop two bits; duplicate+mask the second when absent so both
                // evals sit in one basic block (independent chains -> ILP)
                int f0 = r * 64 + (__ffsll((long long)m) - 1);
                m &= m - 1;
                bool has1 = (m != 0);
                int f1 = has1 ? (r * 64 + __ffsll((long long)m) - 1) : f0;
                if (has1) m &= m - 1;

                float s0 = eval_face(S, f0, px, py);
                float s1 = eval_face(S, f1, px, py);
                sum -= s0 + (has1 ? s1 : 0.0f);

                // alpha saturation: every lane <= -30 -> 1-exp(S) is bitwise
                // 1.0f for both ref and kernel; remaining faces AND remaining
                // scan rounds can't change anything.
                if (__ballot(sum <= -30.0f) == 0xFFFFFFFFFFFFFFFFull) {
                    done = true;
                    break;
                }
            }
        }

        if (live) {
            float alpha = 1.0f - __expf(sum);   // exp(<=-30) -> alpha = 1.0f
            out[1 + q] = alpha;                 // exclusive -> plain store
            c = fabsf(alpha - gt[q]);
        }
    }

    // ---- block loss reduction: one float per block, plain store ----
    for (int off = 32; off > 0; off >>= 1) c += __shfl_down(c, off, 64);
    if (lane == 0) wsum[wave] = c;
    __syncthreads();
    if (threadIdx.x == 0) {
        float s = 0.0f;
        for (int w = 0; w < TPB; ++w) s += wsum[w];
        ws[blockIdx.x] = s;
    }
}

__global__ __launch_bounds__(BLK) void fin2_kernel(
    const float* __restrict__ ws, float* __restrict__ out)
{
    __shared__ float wsum[BLK / 64];
    int t = threadIdx.x;
    float c = (t < NBX) ? ws[t] : 0.0f;
    for (int off = 32; off > 0; off >>= 1) c += __shfl_down(c, off, 64);
    if ((t & 63) == 0) wsum[t >> 6] = c;
    __syncthreads();
    if (t == 0) {
        float s = 0.0f;
        for (int w = 0; w < BLK / 64; ++w) s += wsum[w];
        out[0] = s * (1.0f / (float)NPIX);   // plain store, no zeroing needed
    }
}

extern "C" void kernel_launch(void* const* d_in, const int* in_sizes, int n_in,
                              void* d_out, int out_size, void* d_ws, size_t ws_size,
                              hipStream_t stream)
{
    const float* verts = (const float*)d_in[0];
    const float* gt    = (const float*)d_in[1];
    const int*   faces = (const int*)d_in[2];
    float* out = (float*)d_out;          // out[0]=loss, out[1..]=sil (H*W)
    float* ws  = (float*)d_ws;           // NBX block partials (512 B)

    sil_kernel<<<NBX, BLK, 0, stream>>>(verts, faces, gt, out, ws);
    fin2_kernel<<<1, BLK, 0, stream>>>(ws, out);
}

// Round 10
// 75.513 us; speedup vs baseline: 1.1498x; 1.1498x over previous
//
#include <hip/hip_runtime.h>
#include <math.h>

#define HI 240
#define WI 135
#define NPIX (HI * WI)          // 32400
#define NF 1000
#define NCHUNK 20
#define FCHUNK (NF / NCHUNK)    // 50  (<= 64: single ballot round)
#define BLK 256
#define FREC 4                  // float4 per face record (eval AoS)
#define TW 8                    // tile width (px)
#define TH 8                    // tile height (px)
#define TX_N 17                 // ceil(135/8)
#define TY_N 30                 // 240/8
#define NTILE (TX_N * TY_N)     // 510
#define TPB 4                   // tiles (waves) per block
#define NBX ((NTILE + TPB - 1) / TPB)   // 128

// Eval record in LDS (4 x float4), read via wave-uniform broadcast:
//   r0 = (p0x, p0y, e0x, e0y)   edge 0: v0 -> v1
//   r1 = (p1x, p1y, e1x, e1y)   edge 1: v1 -> v2
//   r2 = (p2x, p2y, e2x, e2y)   edge 2: v2 -> v0
//   r3 = (rden0, rden1, rden2, tz_valid)
// Scan-phase data (bbox + SAT) in SoA float arrays: 4 B stride -> conflict-
// free per-lane gather. SAT edge vectors are pre-multiplied by the triangle
// orientation sign so "triangle side" is always positive.

__device__ __forceinline__ void project(float x, float y, float z,
                                        float& px, float& py) {
#pragma clang fp contract(off)
    // Bitwise-mirrors ref: z=max(v_z,1e-6); px=(1000*(-x)/z + 512)/1024*W; etc.
    float zc = fmaxf(z, 1e-6f);
    px = ((1000.0f * (-x)) / zc + 512.0f) / 1024.0f * (float)WI;
    py = ((1000.0f * (-y)) / zc + 512.0f) / 1024.0f * (float)HI;
}

// One face evaluation, bitwise-matching the reference arithmetic on the
// sign-test cliff (crosses), fast-math on the smooth parts (2e-2 slack).
__device__ __forceinline__ float eval_face(const float4* sf, int f,
                                           float px, float py)
{
    float4 r0v = sf[FREC * f + 0];   // uniform addr -> LDS broadcast
    float4 r1v = sf[FREC * f + 1];
    float4 r2v = sf[FREC * f + 2];
    float4 dv  = sf[FREC * f + 3];

    float a0x = px - r0v.x, a0y = py - r0v.y;
    float a1x = px - r1v.x, a1y = py - r1v.y;
    float a2x = px - r2v.x, a2y = py - r2v.y;

    float c0, c1, c2;
    {
#pragma clang fp contract(off)
        c0 = r0v.z * a0y - r0v.w * a0x;
        c1 = r1v.z * a1y - r1v.w * a1x;
        c2 = r2v.z * a2y - r2v.w * a2x;
    }
    bool pos = (c0 >= 0.0f) & (c1 >= 0.0f) & (c2 >= 0.0f);
    bool neg = (c0 <= 0.0f) & (c1 <= 0.0f) & (c2 <= 0.0f);

    float t0 = fminf(fmaxf((a0x * r0v.z + a0y * r0v.w) * dv.x, 0.0f), 1.0f);
    float t1 = fminf(fmaxf((a1x * r1v.z + a1y * r1v.w) * dv.y, 0.0f), 1.0f);
    float t2 = fminf(fmaxf((a2x * r2v.z + a2y * r2v.w) * dv.z, 0.0f), 1.0f);
    float u0x = a0x - t0 * r0v.z, u0y = a0y - t0 * r0v.w;
    float u1x = a1x - t1 * r1v.z, u1y = a1y - t1 * r1v.w;
    float u2x = a2x - t2 * r2v.z, u2y = a2y - t2 * r2v.w;
    float d20 = u0x * u0x + u0y * u0y;
    float d21 = u1x * u1x + u1y * u1y;
    float d22 = u2x * u2x + u2y * u2y;
    float d2m = fminf(d20, fminf(d21, d22));

    bool inside = pos | neg;
    float uu = (inside ? d2m : -d2m) * 1.0e4f;
    bool valid = (dv.w != 0.0f) & (inside | (d2m <= 9.2102404e-4f));
    float sp;
    if (uu > 16.0f) sp = uu;     // softplus(uu)=uu to <1.2e-7
    else sp = fmaxf(uu, 0.0f) + __logf(1.0f + __expf(-fabsf(uu)));
    return valid ? sp : 0.0f;
}

// Structure notes (R2..R9 post-mortems):
//  - NO device-scope fences / global atomics in the hot path (R2 fence storm).
//  - FUSED staging (R8: separate prep + global round-trip was 5.5us WORSE;
//    in-block recompute beats cross-XCD L3 reads).
//  - Chunk parallelism is what protects straggler boundary tiles (R9:
//    NCHUNK=1 serialized them, +14us). R10: NCHUNK=20 halves R7's tails.
//  - Exclusive (tile,chunk) ownership -> plain store into ws partials (R5).
//  - Alpha-saturation early exit (all lanes <= -30 -> alpha bitwise 1.0f for
//    both ref and kernel) kills interior-tile stragglers (R6, -25us).
//  - SAT tile/triangle cull + 2-wide ILP eval (R7, -4us).
__global__ __launch_bounds__(BLK) void sil_kernel(
    const float* __restrict__ verts, const int* __restrict__ faces,
    float* __restrict__ ws, float* __restrict__ out)
{
    __shared__ float4 sf[FCHUNK * FREC];                       // 3200 B
    __shared__ float sbx0[FCHUNK], sby0[FCHUNK], sbx1[FCHUNK], sby1[FCHUNK];
    __shared__ float sPx[3][FCHUNK], sPy[3][FCHUNK];           // edge origins
    __shared__ float sEx[3][FCHUNK], sEy[3][FCHUNK];           // signed edges
    __shared__ float sRd[3][FCHUNK];                           // 1/den
    __shared__ float sFlag[FCHUNK];                            // 0/1/2

    // out[0] zeroed here (harness poisons 0xAA); only fin touches it later.
    if (blockIdx.x == 0 && blockIdx.y == 0 && threadIdx.x == 0) out[0] = 0.0f;

    // ---- fused staging: thread f builds face record f of this chunk ----
    {
        int f = threadIdx.x;
        if (f < FCHUNK) {
#pragma clang fp contract(off)
            int g = blockIdx.y * FCHUNK + f;
            int i0 = faces[3 * g + 0], i1 = faces[3 * g + 1], i2 = faces[3 * g + 2];
            float x0 = verts[3 * i0 + 0], y0 = verts[3 * i0 + 1], z0 = verts[3 * i0 + 2];
            float x1 = verts[3 * i1 + 0], y1 = verts[3 * i1 + 1], z1 = verts[3 * i1 + 2];
            float x2 = verts[3 * i2 + 0], y2 = verts[3 * i2 + 1], z2 = verts[3 * i2 + 2];

            float p0x, p0y, p1x, p1y, p2x, p2y;
            project(x0, y0, z0, p0x, p0y);
            project(x1, y1, z1, p1x, p1y);
            project(x2, y2, z2, p2x, p2y);

            float e0x = p1x - p0x, e0y = p1y - p0y;
            float e1x = p2x - p1x, e1y = p2y - p1y;
            float e2x = p0x - p2x, e2y = p0y - p2y;
            float den0 = (e0x * e0x + e0y * e0y) + 1e-12f;
            float den1 = (e1x * e1x + e1y * e1y) + 1e-12f;
            float den2 = (e2x * e2x + e2y * e2y) + 1e-12f;
            float rd0 = 1.0f / den0, rd1 = 1.0f / den1, rd2 = 1.0f / den2;

            float tz = ((z0 + z1) + z2) / 3.0f;
            bool tzok = tz > 1e-6f;

            // Pathology rule (provable): fp cross sign flip outside bbox+0.3px
            // needs two simultaneously-ambiguous crosses; safe iff
            // area2 >= 4e-3*lmax^2 and lmax <= 2000px.
            float orient = e0x * e1y - e0y * e1x;   // 2*signed area
            float area2 = fabsf(orient);
            float l2max = fmaxf(den0, fmaxf(den1, den2));
            bool dup = (i0 == i1) || (i1 == i2) || (i2 == i0);
            bool patho = dup || (area2 < 4.0e-3f * l2max) || (l2max > 4.0e6f);

            float bx0, by0, bx1, by1, flag;
            if (!tzok) {               // contribution exactly zero everywhere
                bx0 = 1e30f; by0 = 1e30f; bx1 = -1e30f; by1 = -1e30f; flag = 0.0f;
            } else if (patho) {        // always evaluate, no SAT cull
                bx0 = -1e30f; by0 = -1e30f; bx1 = 1e30f; by1 = 1e30f; flag = 2.0f;
            } else {
                // 0.3 px margin >= sqrt(BLUR)=0.0304 blur band + fp band
                bx0 = fminf(p0x, fminf(p1x, p2x)) - 0.3f;
                by0 = fminf(p0y, fminf(p1y, p2y)) - 0.3f;
                bx1 = fmaxf(p0x, fmaxf(p1x, p2x)) + 0.3f;
                by1 = fmaxf(p0y, fmaxf(p1y, p2y)) + 0.3f;
                flag = 1.0f;
            }

            sf[FREC * f + 0] = make_float4(p0x, p0y, e0x, e0y);
            sf[FREC * f + 1] = make_float4(p1x, p1y, e1x, e1y);
            sf[FREC * f + 2] = make_float4(p2x, p2y, e2x, e2y);
            sf[FREC * f + 3] = make_float4(rd0, rd1, rd2, tzok ? 1.0f : 0.0f);
            sbx0[f] = bx0; sby0[f] = by0; sbx1[f] = bx1; sby1[f] = by1;
            sFlag[f] = flag;
            float sgn = (orient >= 0.0f) ? 1.0f : -1.0f;  // triangle side -> +
            sPx[0][f] = p0x; sPy[0][f] = p0y; sEx[0][f] = sgn * e0x; sEy[0][f] = sgn * e0y; sRd[0][f] = rd0;
            sPx[1][f] = p1x; sPy[1][f] = p1y; sEx[1][f] = sgn * e1x; sEy[1][f] = sgn * e1y; sRd[1][f] = rd1;
            sPx[2][f] = p2x; sPy[2][f] = p2y; sEx[2][f] = sgn * e2x; sEy[2][f] = sgn * e2y; sRd[2][f] = rd2;
        }
    }
    __syncthreads();

    int wave = threadIdx.x >> 6, lane = threadIdx.x & 63;
    int tile = blockIdx.x * TPB + wave;
    if (tile >= NTILE) return;

    int ty = tile / TX_N, tx = tile - ty * TX_N;
    int col = tx * TW + (lane & 7);
    int row = ty * TH + (lane >> 3);
    bool live = col < WI;                  // x-tail tiles partially valid
    int q = row * WI + col;
    float px = (float)col + 0.5f;
    float py = (float)row + 0.5f;
    // wave-uniform 8x8 tile rect (pixel centers)
    float wx0 = (float)(tx * TW) + 0.5f, wx1 = (float)(tx * TW + TW - 1) + 0.5f;
    float wy0 = (float)(ty * TH) + 0.5f, wy1 = (float)(ty * TH + TH - 1) + 0.5f;

    // dead lanes start saturated so they never block the early-exit ballot
    float sum = live ? 0.0f : -1e30f;

    // ---- lane-parallel scan: FCHUNK=50 <= 64 -> single round ----
    bool ov = false;
    if (lane < FCHUNK) {
        int fl = lane;
        ov = !(sbx0[fl] > wx1 || sbx1[fl] < wx0 ||
               sby0[fl] > wy1 || sby1[fl] < wy0);
        if (ov && sFlag[fl] == 1.0f) {
            // SAT: rect separated from triangle by edge k's line with >0.3px
            // margin -> exactly zero contribution for the whole tile.
            // Cross affine in p: max over rect corners =
            // base + max(0,-7*Ey) + max(0,7*Ex).
            bool cull = false;
#pragma unroll
            for (int k = 0; k < 3; ++k) {
                float Ex = sEx[k][fl], Ey = sEy[k][fl];
                float base = Ex * (wy0 - sPy[k][fl]) - Ey * (wx0 - sPx[k][fl]);
                float mx = base + fmaxf(0.0f, -7.0f * Ey)
                                + fmaxf(0.0f,  7.0f * Ex);
                cull |= (mx < 0.0f) & (mx * mx * sRd[k][fl] > 0.09f);
            }
            ov = !cull;
        }
    }
    unsigned long long m = __ballot(ov);

    while (m) {
        // pop two bits; duplicate+mask the second when absent so both evals
        // sit in one basic block (independent chains -> ILP)
        int f0 = __ffsll((long long)m) - 1;
        m &= m - 1;
        bool has1 = (m != 0);
        int f1 = has1 ? (__ffsll((long long)m) - 1) : f0;
        if (has1) m &= m - 1;

        float s0 = eval_face(sf, f0, px, py);
        float s1 = eval_face(sf, f1, px, py);
        sum -= s0 + (has1 ? s1 : 0.0f);

        // alpha saturation: every lane <= -30 -> 1-exp(S) is bitwise 1.0f
        // for both ref and kernel; remaining faces can't change anything.
        if (__ballot(sum <= -30.0f) == 0xFFFFFFFFFFFFFFFFull) break;
    }
    // exclusive ownership of (chunk, pixel) -> plain coalesced store
    if (live) ws[(size_t)blockIdx.y * NPIX + q] = sum;
}

__global__ __launch_bounds__(BLK) void fin_kernel(
    const float* __restrict__ ws, const float* __restrict__ gt,
    float* __restrict__ out)
{
    __shared__ float wsum[BLK / 64];
    int q = blockIdx.x * BLK + threadIdx.x;
    float c = 0.0f;
    if (q < NPIX) {
        float s = 0.0f;
#pragma unroll
        for (int ch = 0; ch < NCHUNK; ++ch) s += ws[(size_t)ch * NPIX + q];
        float alpha = 1.0f - __expf(s);    // exp(very negative) -> 0 -> alpha=1
        out[1 + q] = alpha;
        c = fabsf(alpha - gt[q]);
    }
    for (int off = 32; off > 0; off >>= 1) c += __shfl_down(c, off, 64);
    if ((threadIdx.x & 63) == 0) wsum[threadIdx.x >> 6] = c;
    __syncthreads();
    if (threadIdx.x == 0) {
        float s = 0.0f;
        for (int w = 0; w < BLK / 64; ++w) s += wsum[w];
        atomicAdd(&out[0], s * (1.0f / (float)NPIX));   // out[0] zeroed by sil
    }
}

extern "C" void kernel_launch(void* const* d_in, const int* in_sizes, int n_in,
                              void* d_out, int out_size, void* d_ws, size_t ws_size,
                              hipStream_t stream)
{
    const float* verts = (const float*)d_in[0];
    const float* gt    = (const float*)d_in[1];
    const int*   faces = (const int*)d_in[2];
    float* out = (float*)d_out;          // out[0]=loss, out[1..]=sil (H*W)
    float* ws  = (float*)d_ws;           // NCHUNK * NPIX floats = 2.6 MB partials

    dim3 sgrid(NBX, NCHUNK);             // 128 x 20 = 2560 blocks
    sil_kernel<<<sgrid, BLK, 0, stream>>>(verts, faces, ws, out);

    fin_kernel<<<(NPIX + BLK - 1) / BLK, BLK, 0, stream>>>(ws, gt, out);
}

// Round 11
// 72.666 us; speedup vs baseline: 1.1949x; 1.0392x over previous
//
#include <hip/hip_runtime.h>
#include <math.h>

#define HI 240
#define WI 135
#define NPIX (HI * WI)          // 32400
#define NF 1000
#define NCHUNK 10               // measured optimum: 1 -> +14us, 10 -> best, 20 -> +3us
#define FCHUNK (NF / NCHUNK)    // 100
#define BLK 256
#define FREC 4                  // float4 per face record (eval AoS)
#define TW 8                    // tile width (px)
#define TH 8                    // tile height (px)
#define TX_N 17                 // ceil(135/8)
#define TY_N 30                 // 240/8
#define NTILE (TX_N * TY_N)     // 510
#define TPB 4                   // tiles (waves) per block
#define NBX ((NTILE + TPB - 1) / TPB)   // 128

// Eval record in LDS (4 x float4), read via wave-uniform broadcast:
//   r0 = (p0x, p0y, e0x, e0y)   edge 0: v0 -> v1
//   r1 = (p1x, p1y, e1x, e1y)   edge 1: v1 -> v2
//   r2 = (p2x, p2y, e2x, e2y)   edge 2: v2 -> v0
//   r3 = (rden0, rden1, rden2, tz_valid)
// Scan-phase data (bbox + SAT) in SoA float arrays: 4 B stride -> conflict-
// free per-lane gather. SAT edge vectors are pre-multiplied by the triangle
// orientation sign so "triangle side" is always positive.

__device__ __forceinline__ void project(float x, float y, float z,
                                        float& px, float& py) {
#pragma clang fp contract(off)
    // Bitwise-mirrors ref: z=max(v_z,1e-6); px=(1000*(-x)/z + 512)/1024*W; etc.
    float zc = fmaxf(z, 1e-6f);
    px = ((1000.0f * (-x)) / zc + 512.0f) / 1024.0f * (float)WI;
    py = ((1000.0f * (-y)) / zc + 512.0f) / 1024.0f * (float)HI;
}

// One face evaluation, bitwise-matching the reference arithmetic on the
// sign-test cliff (crosses), fast-math on the smooth parts (2e-2 slack).
__device__ __forceinline__ float eval_face(const float4* sf, int f,
                                           float px, float py)
{
    float4 r0v = sf[FREC * f + 0];   // uniform addr -> LDS broadcast
    float4 r1v = sf[FREC * f + 1];
    float4 r2v = sf[FREC * f + 2];
    float4 dv  = sf[FREC * f + 3];

    float a0x = px - r0v.x, a0y = py - r0v.y;
    float a1x = px - r1v.x, a1y = py - r1v.y;
    float a2x = px - r2v.x, a2y = py - r2v.y;

    float c0, c1, c2;
    {
#pragma clang fp contract(off)
        c0 = r0v.z * a0y - r0v.w * a0x;
        c1 = r1v.z * a1y - r1v.w * a1x;
        c2 = r2v.z * a2y - r2v.w * a2x;
    }
    bool pos = (c0 >= 0.0f) & (c1 >= 0.0f) & (c2 >= 0.0f);
    bool neg = (c0 <= 0.0f) & (c1 <= 0.0f) & (c2 <= 0.0f);

    float t0 = fminf(fmaxf((a0x * r0v.z + a0y * r0v.w) * dv.x, 0.0f), 1.0f);
    float t1 = fminf(fmaxf((a1x * r1v.z + a1y * r1v.w) * dv.y, 0.0f), 1.0f);
    float t2 = fminf(fmaxf((a2x * r2v.z + a2y * r2v.w) * dv.z, 0.0f), 1.0f);
    float u0x = a0x - t0 * r0v.z, u0y = a0y - t0 * r0v.w;
    float u1x = a1x - t1 * r1v.z, u1y = a1y - t1 * r1v.w;
    float u2x = a2x - t2 * r2v.z, u2y = a2y - t2 * r2v.w;
    float d20 = u0x * u0x + u0y * u0y;
    float d21 = u1x * u1x + u1y * u1y;
    float d22 = u2x * u2x + u2y * u2y;
    float d2m = fminf(d20, fminf(d21, d22));

    bool inside = pos | neg;
    float uu = (inside ? d2m : -d2m) * 1.0e4f;
    bool valid = (dv.w != 0.0f) & (inside | (d2m <= 9.2102404e-4f));
    float sp;
    if (uu > 16.0f) sp = uu;     // softplus(uu)=uu to <1.2e-7
    else sp = fmaxf(uu, 0.0f) + __logf(1.0f + __expf(-fabsf(uu)));
    return valid ? sp : 0.0f;
}

// Structure notes (R2..R10 post-mortems):
//  - NO device-scope fences / global atomics in the hot path (R2 fence storm).
//  - FUSED staging (R8: separate prep + global round-trip was 5.5us WORSE).
//  - NCHUNK=10 is the measured optimum (R9: 1 -> +14us; R10: 20 -> +3us).
//  - Exclusive (tile,chunk) ownership -> plain store into ws partials (R5).
//  - Alpha-saturation early exit (all lanes <= -30 -> alpha bitwise 1.0f for
//    both ref and kernel) kills interior-tile stragglers (R6, -25us).
//  - SAT tile/triangle cull (R7, -4us). R11: eval ILP widened 2 -> 4.
__global__ __launch_bounds__(BLK) void sil_kernel(
    const float* __restrict__ verts, const int* __restrict__ faces,
    float* __restrict__ ws, float* __restrict__ out)
{
    __shared__ float4 sf[FCHUNK * FREC];                       // 6400 B
    __shared__ float sbx0[FCHUNK], sby0[FCHUNK], sbx1[FCHUNK], sby1[FCHUNK];
    __shared__ float sPx[3][FCHUNK], sPy[3][FCHUNK];           // edge origins
    __shared__ float sEx[3][FCHUNK], sEy[3][FCHUNK];           // signed edges
    __shared__ float sRd[3][FCHUNK];                           // 1/den
    __shared__ float sFlag[FCHUNK];                            // 0/1/2

    // out[0] zeroed here (harness poisons 0xAA); only fin touches it later.
    if (blockIdx.x == 0 && blockIdx.y == 0 && threadIdx.x == 0) out[0] = 0.0f;

    // ---- fused staging: thread f builds face record f of this chunk ----
    {
        int f = threadIdx.x;
        if (f < FCHUNK) {
#pragma clang fp contract(off)
            int g = blockIdx.y * FCHUNK + f;
            int i0 = faces[3 * g + 0], i1 = faces[3 * g + 1], i2 = faces[3 * g + 2];
            float x0 = verts[3 * i0 + 0], y0 = verts[3 * i0 + 1], z0 = verts[3 * i0 + 2];
            float x1 = verts[3 * i1 + 0], y1 = verts[3 * i1 + 1], z1 = verts[3 * i1 + 2];
            float x2 = verts[3 * i2 + 0], y2 = verts[3 * i2 + 1], z2 = verts[3 * i2 + 2];

            float p0x, p0y, p1x, p1y, p2x, p2y;
            project(x0, y0, z0, p0x, p0y);
            project(x1, y1, z1, p1x, p1y);
            project(x2, y2, z2, p2x, p2y);

            float e0x = p1x - p0x, e0y = p1y - p0y;
            float e1x = p2x - p1x, e1y = p2y - p1y;
            float e2x = p0x - p2x, e2y = p0y - p2y;
            float den0 = (e0x * e0x + e0y * e0y) + 1e-12f;
            float den1 = (e1x * e1x + e1y * e1y) + 1e-12f;
            float den2 = (e2x * e2x + e2y * e2y) + 1e-12f;
            float rd0 = 1.0f / den0, rd1 = 1.0f / den1, rd2 = 1.0f / den2;

            float tz = ((z0 + z1) + z2) / 3.0f;
            bool tzok = tz > 1e-6f;

            // Pathology rule (provable): fp cross sign flip outside bbox+0.3px
            // needs two simultaneously-ambiguous crosses; safe iff
            // area2 >= 4e-3*lmax^2 and lmax <= 2000px.
            float orient = e0x * e1y - e0y * e1x;   // 2*signed area
            float area2 = fabsf(orient);
            float l2max = fmaxf(den0, fmaxf(den1, den2));
            bool dup = (i0 == i1) || (i1 == i2) || (i2 == i0);
            bool patho = dup || (area2 < 4.0e-3f * l2max) || (l2max > 4.0e6f);

            float bx0, by0, bx1, by1, flag;
            if (!tzok) {               // contribution exactly zero everywhere
                bx0 = 1e30f; by0 = 1e30f; bx1 = -1e30f; by1 = -1e30f; flag = 0.0f;
            } else if (patho) {        // always evaluate, no SAT cull
                bx0 = -1e30f; by0 = -1e30f; bx1 = 1e30f; by1 = 1e30f; flag = 2.0f;
            } else {
                // 0.3 px margin >= sqrt(BLUR)=0.0304 blur band + fp band
                bx0 = fminf(p0x, fminf(p1x, p2x)) - 0.3f;
                by0 = fminf(p0y, fminf(p1y, p2y)) - 0.3f;
                bx1 = fmaxf(p0x, fmaxf(p1x, p2x)) + 0.3f;
                by1 = fmaxf(p0y, fmaxf(p1y, p2y)) + 0.3f;
                flag = 1.0f;
            }

            sf[FREC * f + 0] = make_float4(p0x, p0y, e0x, e0y);
            sf[FREC * f + 1] = make_float4(p1x, p1y, e1x, e1y);
            sf[FREC * f + 2] = make_float4(p2x, p2y, e2x, e2y);
            sf[FREC * f + 3] = make_float4(rd0, rd1, rd2, tzok ? 1.0f : 0.0f);
            sbx0[f] = bx0; sby0[f] = by0; sbx1[f] = bx1; sby1[f] = by1;
            sFlag[f] = flag;
            float sgn = (orient >= 0.0f) ? 1.0f : -1.0f;  // triangle side -> +
            sPx[0][f] = p0x; sPy[0][f] = p0y; sEx[0][f] = sgn * e0x; sEy[0][f] = sgn * e0y; sRd[0][f] = rd0;
            sPx[1][f] = p1x; sPy[1][f] = p1y; sEx[1][f] = sgn * e1x; sEy[1][f] = sgn * e1y; sRd[1][f] = rd1;
            sPx[2][f] = p2x; sPy[2][f] = p2y; sEx[2][f] = sgn * e2x; sEy[2][f] = sgn * e2y; sRd[2][f] = rd2;
        }
    }
    __syncthreads();

    int wave = threadIdx.x >> 6, lane = threadIdx.x & 63;
    int tile = blockIdx.x * TPB + wave;
    if (tile >= NTILE) return;

    int ty = tile / TX_N, tx = tile - ty * TX_N;
    int col = tx * TW + (lane & 7);
    int row = ty * TH + (lane >> 3);
    bool live = col < WI;                  // x-tail tiles partially valid
    int q = row * WI + col;
    float px = (float)col + 0.5f;
    float py = (float)row + 0.5f;
    // wave-uniform 8x8 tile rect (pixel centers)
    float wx0 = (float)(tx * TW) + 0.5f, wx1 = (float)(tx * TW + TW - 1) + 0.5f;
    float wy0 = (float)(ty * TH) + 0.5f, wy1 = (float)(ty * TH + TH - 1) + 0.5f;

    // dead lanes start saturated so they never block the early-exit ballot
    float sum = live ? 0.0f : -1e30f;
    bool done = false;

    for (int r = 0; r < (FCHUNK + 63) / 64 && !done; ++r) {
        int fl = r * 64 + lane;
        bool ov = false;
        if (fl < FCHUNK) {
            ov = !(sbx0[fl] > wx1 || sbx1[fl] < wx0 ||
                   sby0[fl] > wy1 || sby1[fl] < wy0);
            if (ov && sFlag[fl] == 1.0f) {
                // SAT: rect separated from triangle by edge k's line with
                // >0.3px margin -> exactly zero contribution for the whole
                // tile. Cross affine in p: max over rect corners =
                // base + max(0,-7*Ey) + max(0,7*Ex).
                bool cull = false;
#pragma unroll
                for (int k = 0; k < 3; ++k) {
                    float Ex = sEx[k][fl], Ey = sEy[k][fl];
                    float base = Ex * (wy0 - sPy[k][fl]) - Ey * (wx0 - sPx[k][fl]);
                    float mx = base + fmaxf(0.0f, -7.0f * Ey)
                                    + fmaxf(0.0f,  7.0f * Ex);
                    cull |= (mx < 0.0f) & (mx * mx * sRd[k][fl] > 0.09f);
                }
                ov = !cull;
            }
        }
        unsigned long long m = __ballot(ov);

        while (m) {
            // pop up to FOUR bits; absent slots duplicate f0 and are masked,
            // so all four evals sit in one basic block (independent
            // ~150-cycle chains -> 4-way ILP on straggler waves).
            int f0 = r * 64 + (__ffsll((long long)m) - 1);
            m &= m - 1;
            bool h1 = (m != 0);
            int f1 = h1 ? (r * 64 + __ffsll((long long)m) - 1) : f0;
            if (h1) m &= m - 1;
            bool h2 = (m != 0);
            int f2 = h2 ? (r * 64 + __ffsll((long long)m) - 1) : f0;
            if (h2) m &= m - 1;
            bool h3 = (m != 0);
            int f3 = h3 ? (r * 64 + __ffsll((long long)m) - 1) : f0;
            if (h3) m &= m - 1;

            float s0 = eval_face(sf, f0, px, py);
            float s1 = eval_face(sf, f1, px, py);
            float s2 = eval_face(sf, f2, px, py);
            float s3 = eval_face(sf, f3, px, py);
            sum -= s0 + (h1 ? s1 : 0.0f) + (h2 ? s2 : 0.0f) + (h3 ? s3 : 0.0f);

            // alpha saturation: every lane <= -30 -> 1-exp(S) is bitwise 1.0f
            // for both ref and kernel; remaining faces can't change anything.
            if (__ballot(sum <= -30.0f) == 0xFFFFFFFFFFFFFFFFull) {
                done = true;
                break;
            }
        }
    }
    // exclusive ownership of (chunk, pixel) -> plain coalesced store
    if (live) ws[(size_t)blockIdx.y * NPIX + q] = sum;
}

__global__ __launch_bounds__(BLK) void fin_kernel(
    const float* __restrict__ ws, const float* __restrict__ gt,
    float* __restrict__ out)
{
    __shared__ float wsum[BLK / 64];
    int q = blockIdx.x * BLK + threadIdx.x;
    float c = 0.0f;
    if (q < NPIX) {
        float s = 0.0f;
#pragma unroll
        for (int ch = 0; ch < NCHUNK; ++ch) s += ws[(size_t)ch * NPIX + q];
        float alpha = 1.0f - __expf(s);    // exp(very negative) -> 0 -> alpha=1
        out[1 + q] = alpha;
        c = fabsf(alpha - gt[q]);
    }
    for (int off = 32; off > 0; off >>= 1) c += __shfl_down(c, off, 64);
    if ((threadIdx.x & 63) == 0) wsum[threadIdx.x >> 6] = c;
    __syncthreads();
    if (threadIdx.x == 0) {
        float s = 0.0f;
        for (int w = 0; w < BLK / 64; ++w) s += wsum[w];
        atomicAdd(&out[0], s * (1.0f / (float)NPIX));   // out[0] zeroed by sil
    }
}

extern "C" void kernel_launch(void* const* d_in, const int* in_sizes, int n_in,
                              void* d_out, int out_size, void* d_ws, size_t ws_size,
                              hipStream_t stream)
{
    const float* verts = (const float*)d_in[0];
    const float* gt    = (const float*)d_in[1];
    const int*   faces = (const int*)d_in[2];
    float* out = (float*)d_out;          // out[0]=loss, out[1..]=sil (H*W)
    float* ws  = (float*)d_ws;           // NCHUNK * NPIX floats = 1.3 MB partials

    dim3 sgrid(NBX, NCHUNK);             // 128 x 10 = 1280 blocks
    sil_kernel<<<sgrid, BLK, 0, stream>>>(verts, faces, ws, out);

    fin_kernel<<<(NPIX + BLK - 1) / BLK, BLK, 0, stream>>>(ws, gt, out);
}